// Round 1
// baseline (415.961 us; speedup 1.0000x reference)
//
#include <hip/hip_runtime.h>
#include <hip/hip_bf16.h>

// Fused causal MHA for B=256,T=128,H=8,D=256,C=256.
// One block per (h,b): 512 threads (8 waves), 160KB dynamic LDS.
// bf16 MFMA (16x16x32) everywhere, fp32 accumulate, scale folded into Q.

#define TT 128
#define CC 256
#define DD 256
#define NB 256

typedef __attribute__((ext_vector_type(8))) short short8;
typedef __attribute__((ext_vector_type(4))) float f32x4;

__device__ __forceinline__ unsigned short f2bf(float x) {
    union { float f; unsigned u; } v; v.f = x;
    unsigned r = v.u + 0x7FFFu + ((v.u >> 16) & 1u);  // round-to-nearest-even
    return (unsigned short)(r >> 16);
}
__device__ __forceinline__ unsigned pk2(float a, float b) {
    return (unsigned)f2bf(a) | ((unsigned)f2bf(b) << 16);
}
// XOR swizzle within a row: spreads stride-256B/512B rows across banks (T2)
__device__ __forceinline__ int swz(int row, int byteInRow) {
    return byteInRow ^ ((row & 7) << 4);
}

__global__ __launch_bounds__(512, 2) void mha_fused(
    const float* __restrict__ x,
    const float* __restrict__ Wq, const float* __restrict__ bq,
    const float* __restrict__ Wk, const float* __restrict__ bk,
    const float* __restrict__ Wv, const float* __restrict__ bv,
    const float* __restrict__ Wp, const float* __restrict__ bp,
    float* __restrict__ out)
{
    extern __shared__ __align__(16) char lds[];
    char* bufX  = lds;            // 64KB: X [128][256] bf16 (rows 512B); later VT [256][128] (rows 256B)
    char* bufKV = lds + 65536;    // 64KB: Q-scratch -> K [128][256] -> P [128][128] -> O [128][256]
    char* bufW  = lds + 131072;   // 32KB: weight chunk [64][256] bf16; softmax reduce scratch

    const int tid = threadIdx.x;
    const int w  = tid >> 6, l = tid & 63;
    const int lg = l >> 4, lr = l & 15;
    const int mq = w & 3;         // wave's 32-row t-band
    const int nh = w >> 2;        // wave's n-half
    const int bid = blockIdx.x;
    const int h = bid >> 8, b = bid & 255;

    const int am0 = mq * 32 + lr; // A-fragment rows (m = lane&15)
    const int am1 = am0 + 16;

    // ---- stage X: fp32 -> bf16, swizzled [128][256] ----
    {
        const float4* xs = (const float4*)(x + (size_t)b * (TT * CC));
        #pragma unroll
        for (int i = 0; i < 16; ++i) {
            int e4 = tid + i * 512;
            float4 v = xs[e4];
            int e = e4 * 4, r = e >> 8, c = e & 255;
            uint2 u; u.x = pk2(v.x, v.y); u.y = pk2(v.z, v.w);
            *(uint2*)(bufX + r * 512 + swz(r, c * 2)) = u;
        }
    }

    auto stage_w = [&](const float* Wsrc, int r0) {
        const float4* ws = (const float4*)(Wsrc + (size_t)r0 * CC);
        #pragma unroll
        for (int i = 0; i < 8; ++i) {
            int e4 = tid + i * 512;
            float4 v = ws[e4];
            int e = e4 * 4, r = e >> 8, c = e & 255;
            uint2 u; u.x = pk2(v.x, v.y); u.y = pk2(v.z, v.w);
            *(uint2*)(bufW + r * 512 + swz(r, c * 2)) = u;
        }
    };

    // acc[mt][nt] = A[32t x 256] * Wchunk^T (wave covers [32t x 32n] of the 64-col chunk)
    auto mm_chunk = [&](const char* Ab, f32x4 (&acc)[2][2]) {
        #pragma unroll
        for (int mt = 0; mt < 2; ++mt)
            #pragma unroll
            for (int nt = 0; nt < 2; ++nt)
                acc[mt][nt] = f32x4{0.f, 0.f, 0.f, 0.f};
        const int br0 = nh * 32 + lr, br1 = br0 + 16;
        #pragma unroll
        for (int ks = 0; ks < 8; ++ks) {
            int cb = ks * 64 + lg * 16;
            short8 a0 = *(const short8*)(Ab + am0 * 512 + swz(am0, cb));
            short8 a1 = *(const short8*)(Ab + am1 * 512 + swz(am1, cb));
            short8 b0 = *(const short8*)(bufW + br0 * 512 + swz(br0, cb));
            short8 b1 = *(const short8*)(bufW + br1 * 512 + swz(br1, cb));
            acc[0][0] = __builtin_amdgcn_mfma_f32_16x16x32_bf16(a0, b0, acc[0][0], 0, 0, 0);
            acc[0][1] = __builtin_amdgcn_mfma_f32_16x16x32_bf16(a0, b1, acc[0][1], 0, 0, 0);
            acc[1][0] = __builtin_amdgcn_mfma_f32_16x16x32_bf16(a1, b0, acc[1][0], 0, 0, 0);
            acc[1][1] = __builtin_amdgcn_mfma_f32_16x16x32_bf16(a1, b1, acc[1][1], 0, 0, 0);
        }
    };

    // ---- Q phase: compute Q (scale 1/16 folded), round-trip via per-band scratch ----
    char* qscr = bufKV + mq * 16384;  // [32][256] bf16 per t-band
    #pragma unroll
    for (int ch = 0; ch < 4; ++ch) {
        stage_w(Wq + (size_t)h * DD * CC, ch * 64);
        __syncthreads();
        f32x4 acc[2][2];
        mm_chunk(bufX, acc);
        #pragma unroll
        for (int mt = 0; mt < 2; ++mt)
        #pragma unroll
        for (int nt = 0; nt < 2; ++nt) {
            int d = ch * 64 + nh * 32 + nt * 16 + lr;
            float bias = bq[h * DD + d];
            #pragma unroll
            for (int r = 0; r < 4; ++r) {
                int tl = mt * 16 + lg * 4 + r;
                *(unsigned short*)(qscr + tl * 512 + swz(tl, d * 2)) =
                    f2bf((acc[mt][nt][r] + bias) * 0.0625f);
            }
        }
        __syncthreads();
    }
    // read back Q as A-fragments (held in registers through S-phase)
    short8 qf[2][8];
    #pragma unroll
    for (int mt = 0; mt < 2; ++mt)
    #pragma unroll
    for (int ks = 0; ks < 8; ++ks) {
        int tl = mt * 16 + lr;
        qf[mt][ks] = *(const short8*)(qscr + tl * 512 + swz(tl, ks * 64 + lg * 16));
    }

    // ---- K phase: K -> bufKV [128][256] bf16 swizzled ----
    #pragma unroll
    for (int ch = 0; ch < 4; ++ch) {
        stage_w(Wk + (size_t)h * DD * CC, ch * 64);
        __syncthreads();
        f32x4 acc[2][2];
        mm_chunk(bufX, acc);
        #pragma unroll
        for (int mt = 0; mt < 2; ++mt)
        #pragma unroll
        for (int nt = 0; nt < 2; ++nt) {
            int d = ch * 64 + nh * 32 + nt * 16 + lr;
            float bias = bk[h * DD + d];
            #pragma unroll
            for (int r = 0; r < 4; ++r) {
                int s = mq * 32 + mt * 16 + lg * 4 + r;
                *(unsigned short*)(bufKV + s * 512 + swz(s, d * 2)) = f2bf(acc[mt][nt][r] + bias);
            }
        }
        __syncthreads();
    }

    // ---- V phase: V held in registers, then write V^T -> bufX (X dead after this) ----
    uint2 vreg[4][2][2];
    #pragma unroll
    for (int ch = 0; ch < 4; ++ch) {
        stage_w(Wv + (size_t)h * DD * CC, ch * 64);
        __syncthreads();
        f32x4 acc[2][2];
        mm_chunk(bufX, acc);
        #pragma unroll
        for (int mt = 0; mt < 2; ++mt)
        #pragma unroll
        for (int nt = 0; nt < 2; ++nt) {
            int d = ch * 64 + nh * 32 + nt * 16 + lr;
            float bias = bv[h * DD + d];
            vreg[ch][mt][nt].x = pk2(acc[mt][nt][0] + bias, acc[mt][nt][1] + bias);
            vreg[ch][mt][nt].y = pk2(acc[mt][nt][2] + bias, acc[mt][nt][3] + bias);
        }
        __syncthreads();
    }
    // VT [256 d][128 s] bf16 rows 256B, swizzled; 4 consecutive s packed per write
    #pragma unroll
    for (int ch = 0; ch < 4; ++ch)
    #pragma unroll
    for (int mt = 0; mt < 2; ++mt)
    #pragma unroll
    for (int nt = 0; nt < 2; ++nt) {
        int d  = ch * 64 + nh * 32 + nt * 16 + lr;
        int s0 = mq * 32 + mt * 16 + lg * 4;
        *(uint2*)(bufX + d * 256 + swz(d, s0 * 2)) = vreg[ch][mt][nt];
    }

    // ---- S = Q K^T (already scaled), causal mask, softmax -> P (bf16) ----
    f32x4 sacc[2][4];
    #pragma unroll
    for (int mt = 0; mt < 2; ++mt)
        #pragma unroll
        for (int nt = 0; nt < 4; ++nt)
            sacc[mt][nt] = f32x4{0.f, 0.f, 0.f, 0.f};
    #pragma unroll
    for (int ks = 0; ks < 8; ++ks) {
        int cb = ks * 64 + lg * 16;
        short8 kb[4];
        #pragma unroll
        for (int nt = 0; nt < 4; ++nt) {
            int sr = nh * 64 + nt * 16 + lr;
            kb[nt] = *(const short8*)(bufKV + sr * 512 + swz(sr, cb));
        }
        #pragma unroll
        for (int mt = 0; mt < 2; ++mt)
            #pragma unroll
            for (int nt = 0; nt < 4; ++nt)
                sacc[mt][nt] = __builtin_amdgcn_mfma_f32_16x16x32_bf16(qf[mt][ks], kb[nt], sacc[mt][nt], 0, 0, 0);
    }

    float* redM = (float*)bufW;            // [2][128]
    float* redS = (float*)(bufW + 1024);   // [2][128]
    float rmax[2][4], rsum[2][4];
    #pragma unroll
    for (int mt = 0; mt < 2; ++mt)
    #pragma unroll
    for (int r = 0; r < 4; ++r) {
        int t = mq * 32 + mt * 16 + lg * 4 + r;
        float m = -1e30f;
        #pragma unroll
        for (int nt = 0; nt < 4; ++nt) {
            int s = nh * 64 + nt * 16 + lr;
            if (s > t) sacc[mt][nt][r] = -1e30f;
            m = fmaxf(m, sacc[mt][nt][r]);
        }
        m = fmaxf(m, __shfl_xor(m, 1));
        m = fmaxf(m, __shfl_xor(m, 2));
        m = fmaxf(m, __shfl_xor(m, 4));
        m = fmaxf(m, __shfl_xor(m, 8));
        rmax[mt][r] = m;
    }
    if (lr == 0) {
        #pragma unroll
        for (int mt = 0; mt < 2; ++mt)
        #pragma unroll
        for (int r = 0; r < 4; ++r)
            redM[nh * 128 + mq * 32 + mt * 16 + lg * 4 + r] = rmax[mt][r];
    }
    __syncthreads();
    #pragma unroll
    for (int mt = 0; mt < 2; ++mt)
    #pragma unroll
    for (int r = 0; r < 4; ++r) {
        int t = mq * 32 + mt * 16 + lg * 4 + r;
        float m = fmaxf(redM[t], redM[128 + t]);
        float ssum = 0.f;
        #pragma unroll
        for (int nt = 0; nt < 4; ++nt) {
            float p = __expf(sacc[mt][nt][r] - m);
            sacc[mt][nt][r] = p;
            ssum += p;
        }
        ssum += __shfl_xor(ssum, 1);
        ssum += __shfl_xor(ssum, 2);
        ssum += __shfl_xor(ssum, 4);
        ssum += __shfl_xor(ssum, 8);
        rsum[mt][r] = ssum;
    }
    if (lr == 0) {
        #pragma unroll
        for (int mt = 0; mt < 2; ++mt)
        #pragma unroll
        for (int r = 0; r < 4; ++r)
            redS[nh * 128 + mq * 32 + mt * 16 + lg * 4 + r] = rsum[mt][r];
    }
    __syncthreads();
    // P -> bufKV[0:32KB): [128 t][128 s] bf16 rows 256B swizzled (K fully consumed)
    #pragma unroll
    for (int mt = 0; mt < 2; ++mt)
    #pragma unroll
    for (int r = 0; r < 4; ++r) {
        int t = mq * 32 + mt * 16 + lg * 4 + r;
        float inv = 1.0f / (redS[t] + redS[128 + t]);
        #pragma unroll
        for (int nt = 0; nt < 4; ++nt) {
            int s = nh * 64 + nt * 16 + lr;
            *(unsigned short*)(bufKV + t * 256 + swz(t, s * 2)) = f2bf(sacc[mt][nt][r] * inv);
        }
    }
    __syncthreads();

    // ---- O = P V : wave covers [32 t x 128 d] ----
    f32x4 oacc[2][8];
    #pragma unroll
    for (int mt = 0; mt < 2; ++mt)
        #pragma unroll
        for (int nd = 0; nd < 8; ++nd)
            oacc[mt][nd] = f32x4{0.f, 0.f, 0.f, 0.f};
    #pragma unroll
    for (int ks = 0; ks < 4; ++ks) {
        int sb = ks * 64 + lg * 16;
        short8 pa0 = *(const short8*)(bufKV + am0 * 256 + swz(am0, sb));
        short8 pa1 = *(const short8*)(bufKV + am1 * 256 + swz(am1, sb));
        #pragma unroll
        for (int nd = 0; nd < 8; ++nd) {
            int d = nh * 128 + nd * 16 + lr;
            short8 vb = *(const short8*)(bufX + d * 256 + swz(d, sb));
            oacc[0][nd] = __builtin_amdgcn_mfma_f32_16x16x32_bf16(pa0, vb, oacc[0][nd], 0, 0, 0);
            oacc[1][nd] = __builtin_amdgcn_mfma_f32_16x16x32_bf16(pa1, vb, oacc[1][nd], 0, 0, 0);
        }
    }
    __syncthreads();  // all P/VT reads complete before O overwrites bufKV
    #pragma unroll
    for (int mt = 0; mt < 2; ++mt)
    #pragma unroll
    for (int nd = 0; nd < 8; ++nd)
    #pragma unroll
    for (int r = 0; r < 4; ++r) {
        int t = mq * 32 + mt * 16 + lg * 4 + r;
        int d = nh * 128 + nd * 16 + lr;
        *(unsigned short*)(bufKV + t * 512 + swz(t, d * 2)) = f2bf(oacc[mt][nd][r]);
    }
    __syncthreads();

    // ---- OUT = O Wp^T + bp -> global fp32 ----
    #pragma unroll
    for (int ch = 0; ch < 4; ++ch) {
        stage_w(Wp, ch * 64);
        __syncthreads();
        f32x4 acc[2][2];
        mm_chunk(bufKV, acc);
        #pragma unroll
        for (int mt = 0; mt < 2; ++mt)
        #pragma unroll
        for (int nt = 0; nt < 2; ++nt) {
            int e = ch * 64 + nh * 32 + nt * 16 + lr;
            float bias = bp[e];
            #pragma unroll
            for (int r = 0; r < 4; ++r) {
                int t = mq * 32 + mt * 16 + lg * 4 + r;
                out[((size_t)bid * TT + t) * DD + e] = acc[mt][nt][r] + bias;
            }
        }
        __syncthreads();
    }
}

extern "C" void kernel_launch(void* const* d_in, const int* in_sizes, int n_in,
                              void* d_out, int out_size, void* d_ws, size_t ws_size,
                              hipStream_t stream) {
    (void)in_sizes; (void)n_in; (void)d_ws; (void)ws_size; (void)out_size;
    hipFuncSetAttribute((const void*)mha_fused,
                        hipFuncAttributeMaxDynamicSharedMemorySize, 163840);
    mha_fused<<<dim3(2048), dim3(512), 163840, stream>>>(
        (const float*)d_in[0],
        (const float*)d_in[1], (const float*)d_in[2],
        (const float*)d_in[3], (const float*)d_in[4],
        (const float*)d_in[5], (const float*)d_in[6],
        (const float*)d_in[7], (const float*)d_in[8],
        (float*)d_out);
}

// Round 2
// 370.266 us; speedup vs baseline: 1.1234x; 1.1234x over previous
//
#include <hip/hip_runtime.h>
#include <hip/hip_bf16.h>
#include <stdint.h>

// Fused causal MHA, B=256,T=128,H=8,D=256,C=256. One block per (h,b).
// Round 2: pre-converted bf16+pre-swizzled x/W in d_ws (needs ~19.2MB),
// global_load_lds staging, 3-slot W ring with counted vmcnt + raw s_barrier.

#define TT 128
#define CC 256
#define DD 256

typedef __attribute__((ext_vector_type(8))) short short8;
typedef __attribute__((ext_vector_type(4))) float f32x4;

// LDS map (160KB): [0,64K) X -> later O ; [64K,112K) 3x16K W ring (slot2 doubles
// as softmax scratch during the softmax phases); [112K,144K) QK chunk pairs -> P;
// [144K,160K) 2x8K V^T chunks.
#define LDS_W   65536
#define LDS_QK  114688
#define LDS_VT  147456

// ws map
#define WS_X    0u
#define WS_WQ   16777216u
#define WS_WK   (16777216u + 1048576u)
#define WS_WV   (16777216u + 2097152u)
#define WS_WP   (16777216u + 3145728u)
// total ws need = 20054016 bytes

#define VMCNT2() asm volatile("s_waitcnt vmcnt(2)" ::: "memory")
#define VMCNT0() asm volatile("s_waitcnt vmcnt(0)" ::: "memory")
#define LGKM0()  asm volatile("s_waitcnt lgkmcnt(0)" ::: "memory")
#define BAR()    do { asm volatile("" ::: "memory"); __builtin_amdgcn_s_barrier(); asm volatile("" ::: "memory"); } while (0)

__device__ __forceinline__ unsigned short f2bf(float x) {
    union { float f; unsigned u; } v; v.f = x;
    unsigned r = v.u + 0x7FFFu + ((v.u >> 16) & 1u);
    return (unsigned short)(r >> 16);
}
__device__ __forceinline__ unsigned pk2(float a, float b) {
    return (unsigned)f2bf(a) | ((unsigned)f2bf(b) << 16);
}

typedef __attribute__((address_space(3))) uint32_t lds_u32;
typedef __attribute__((address_space(1))) const uint32_t glb_u32;

// ---------------- pre-convert kernel: fp32 -> bf16, pre-swizzled rows ----------------
__global__ void convert_pre(const float* __restrict__ x,
                            const float* __restrict__ Wq, const float* __restrict__ Wk,
                            const float* __restrict__ Wv, const float* __restrict__ Wp,
                            char* __restrict__ ws) {
    const int NX = 2097152, NW = 131072, NP = 16384;   // float4 counts
    const int total = NX + 3 * NW + NP;
    for (int i = blockIdx.x * blockDim.x + threadIdx.x; i < total;
         i += gridDim.x * blockDim.x) {
        const float4* src; size_t ob; int li;
        if (i < NX)              { src = (const float4*)x;  ob = WS_X;  li = i; }
        else if (i < NX + NW)    { src = (const float4*)Wq; ob = WS_WQ; li = i - NX; }
        else if (i < NX + 2*NW)  { src = (const float4*)Wk; ob = WS_WK; li = i - NX - NW; }
        else if (i < NX + 3*NW)  { src = (const float4*)Wv; ob = WS_WV; li = i - NX - 2*NW; }
        else                     { src = (const float4*)Wp; ob = WS_WP; li = i - NX - 3*NW; }
        float4 v = src[li];
        uint2 u; u.x = pk2(v.x, v.y); u.y = pk2(v.z, v.w);
        int row = li >> 6, c4 = li & 63;     // 256-elem rows -> 512B bf16 rows
        *(uint2*)(ws + ob + (size_t)row * 512 + ((c4 * 8) ^ ((row & 7) << 4))) = u;
    }
}

// ---------------- main fused kernel ----------------
__global__ __launch_bounds__(512, 2) void mha_fused(
    const char* __restrict__ ws,
    const float* __restrict__ bq, const float* __restrict__ bk,
    const float* __restrict__ bv, const float* __restrict__ bp,
    float* __restrict__ out)
{
    extern __shared__ __align__(16) char lds[];
    const int tid = threadIdx.x;
    const int w  = tid >> 6, l = tid & 63;
    const int lg = l >> 4, lr = l & 15;
    const int mq = w & 3, nh = w >> 2;
    const int bid = blockIdx.x;
    const int h = bid >> 8, b = bid & 255;
    const int am0 = mq * 32 + lr, am1 = am0 + 16;

    auto gl16 = [&](const char* g, int loff) {
        __builtin_amdgcn_global_load_lds((glb_u32*)g, (lds_u32*)(lds + loff), 16, 0, 0);
    };
    auto chunk_src = [&](int idx) -> const char* {
        if (idx < 16) {
            int c = idx >> 1;
            return ws + ((idx & 1) ? WS_WK : WS_WQ) + (size_t)h * 131072 + (size_t)c * 16384;
        } else if (idx < 24) {
            return ws + WS_WV + (size_t)h * 131072 + (size_t)(idx - 16) * 16384;
        }
        return ws + WS_WP + (size_t)(idx - 24) * 16384;
    };
    auto issue_chunk = [&](int idx) {
        const char* g = chunk_src(idx) + tid * 16;
        int loff = LDS_W + (idx % 3) * 16384 + tid * 16;
        gl16(g, loff);
        gl16(g + 8192, loff + 8192);
    };
    // A [128][512B rows, swz8] x Wchunk^T [32 rows][512B, swz8] -> acc[2] (mt), wave tile 32t x 16n
    auto proj_mm = [&](int Aoff, int slot, f32x4* acc) {
        acc[0] = f32x4{0.f,0.f,0.f,0.f};
        acc[1] = f32x4{0.f,0.f,0.f,0.f};
        const char* Wb = lds + LDS_W + slot * 16384;
        const char* Ab = lds + Aoff;
        const int br = nh * 16 + lr;
        #pragma unroll
        for (int ks = 0; ks < 8; ++ks) {
            int cb = ks * 64 + lg * 16;
            short8 b0 = *(const short8*)(Wb + br * 512 + (cb ^ ((br & 7) << 4)));
            short8 a0 = *(const short8*)(Ab + am0 * 512 + (cb ^ ((am0 & 7) << 4)));
            short8 a1 = *(const short8*)(Ab + am1 * 512 + (cb ^ ((am1 & 7) << 4)));
            acc[0] = __builtin_amdgcn_mfma_f32_16x16x32_bf16(a0, b0, acc[0], 0, 0, 0);
            acc[1] = __builtin_amdgcn_mfma_f32_16x16x32_bf16(a1, b0, acc[1], 0, 0, 0);
        }
    };

    f32x4 sacc[2][4];
    #pragma unroll
    for (int i = 0; i < 2; ++i)
        #pragma unroll
        for (int j = 0; j < 4; ++j) sacc[i][j] = f32x4{0.f,0.f,0.f,0.f};

    // S += Q_c * K_c^T  (chunk width 32 = one MFMA K)
    auto s_accum = [&](int cp) {
        const char* qs  = lds + LDS_QK + (cp & 1) * 16384;
        const char* ks2 = qs + 8192;
        short8 qa[2], kb[4];
        #pragma unroll
        for (int mt = 0; mt < 2; ++mt) {
            int row = mq * 32 + mt * 16 + lr;
            qa[mt] = *(const short8*)(qs + row * 64 + ((lg * 16) ^ (((row >> 2) & 3) << 4)));
        }
        #pragma unroll
        for (int nt = 0; nt < 4; ++nt) {
            int srow = nh * 64 + nt * 16 + lr;
            kb[nt] = *(const short8*)(ks2 + srow * 64 + ((lg * 16) ^ (((srow >> 2) & 3) << 4)));
        }
        #pragma unroll
        for (int mt = 0; mt < 2; ++mt)
            #pragma unroll
            for (int nt = 0; nt < 4; ++nt)
                sacc[mt][nt] = __builtin_amdgcn_mfma_f32_16x16x32_bf16(qa[mt], kb[nt], sacc[mt][nt], 0, 0, 0);
    };

    // ---- prologue: X (8 loads) + chunks 0,1 ----
    {
        const char* xs = ws + WS_X + (size_t)b * 65536 + tid * 16;
        #pragma unroll
        for (int j = 0; j < 8; ++j) gl16(xs + j * 8192, tid * 16 + j * 8192);
        issue_chunk(0);
        issue_chunk(1);
    }
    VMCNT2(); BAR();

    // ---- QK phases: Q_c (S_{c-1} rides along), K_c ----
    #pragma unroll
    for (int c = 0; c < 8; ++c) {
        // Q_c  (consumer 2c, issues 2c+2)
        issue_chunk(2 * c + 2);
        {
            f32x4 acc[2];
            proj_mm(0, (2 * c) % 3, acc);
            if (c > 0) s_accum(c - 1);
            float bias = bq[h * DD + c * 32 + nh * 16 + lr];
            char* qs = lds + LDS_QK + (c & 1) * 16384;
            #pragma unroll
            for (int mt = 0; mt < 2; ++mt)
                #pragma unroll
                for (int r = 0; r < 4; ++r) {
                    int t = mq * 32 + mt * 16 + lg * 4 + r;
                    *(unsigned short*)(qs + t * 64 + (((nh * 16 + lr) * 2) ^ (((t >> 2) & 3) << 4)))
                        = f2bf((acc[mt][r] + bias) * 0.0625f);
                }
        }
        LGKM0(); VMCNT2(); BAR();
        // K_c  (consumer 2c+1, issues 2c+3)
        issue_chunk(2 * c + 3);
        {
            f32x4 acc[2];
            proj_mm(0, (2 * c + 1) % 3, acc);
            float bias = bk[h * DD + c * 32 + nh * 16 + lr];
            char* ksl = lds + LDS_QK + (c & 1) * 16384 + 8192;
            #pragma unroll
            for (int mt = 0; mt < 2; ++mt)
                #pragma unroll
                for (int r = 0; r < 4; ++r) {
                    int s = mq * 32 + mt * 16 + lg * 4 + r;
                    *(unsigned short*)(ksl + s * 64 + (((nh * 16 + lr) * 2) ^ (((s >> 2) & 3) << 4)))
                        = f2bf(acc[mt][r] + bias);
                }
        }
        LGKM0(); VMCNT2(); BAR();
    }

    s_accum(7);   // S tail (reads slot1; no barrier needed before V phases)

    // ---- V phases: V kept in registers (bf16-packed) ----
    uint2 vreg[8][2];
    #pragma unroll
    for (int c = 0; c < 8; ++c) {
        int j = 16 + c;
        issue_chunk(j + 2);          // up to chunk 25
        f32x4 acc[2];
        proj_mm(0, j % 3, acc);
        float bias = bv[h * DD + c * 32 + nh * 16 + lr];
        #pragma unroll
        for (int mt = 0; mt < 2; ++mt) {
            vreg[c][mt].x = pk2(acc[mt][0] + bias, acc[mt][1] + bias);
            vreg[c][mt].y = pk2(acc[mt][2] + bias, acc[mt][3] + bias);
        }
        LGKM0(); VMCNT2(); BAR();
    }

    // ---- softmax (scratch in W slot 2: safe, in-flight chunks 24,25 -> slots 0,1) ----
    float* redM = (float*)(lds + LDS_W + 2 * 16384);
    float* redS = redM + 256;
    float rmax[2][4];
    #pragma unroll
    for (int mt = 0; mt < 2; ++mt)
        #pragma unroll
        for (int r = 0; r < 4; ++r) {
            int t = mq * 32 + mt * 16 + lg * 4 + r;
            float m = -1e30f;
            #pragma unroll
            for (int nt = 0; nt < 4; ++nt) {
                int s = nh * 64 + nt * 16 + lr;
                if (s > t) sacc[mt][nt][r] = -1e30f;
                m = fmaxf(m, sacc[mt][nt][r]);
            }
            m = fmaxf(m, __shfl_xor(m, 1));
            m = fmaxf(m, __shfl_xor(m, 2));
            m = fmaxf(m, __shfl_xor(m, 4));
            m = fmaxf(m, __shfl_xor(m, 8));
            rmax[mt][r] = m;
        }
    if (lr == 0) {
        #pragma unroll
        for (int mt = 0; mt < 2; ++mt)
            #pragma unroll
            for (int r = 0; r < 4; ++r)
                redM[nh * 128 + mq * 32 + mt * 16 + lg * 4 + r] = rmax[mt][r];
    }
    LGKM0(); BAR();
    float rsum[2][4];
    #pragma unroll
    for (int mt = 0; mt < 2; ++mt)
        #pragma unroll
        for (int r = 0; r < 4; ++r) {
            int t = mq * 32 + mt * 16 + lg * 4 + r;
            float m = fmaxf(redM[t], redM[128 + t]);
            float ssum = 0.f;
            #pragma unroll
            for (int nt = 0; nt < 4; ++nt) {
                float p = __expf(sacc[mt][nt][r] - m);
                sacc[mt][nt][r] = p;
                ssum += p;
            }
            ssum += __shfl_xor(ssum, 1);
            ssum += __shfl_xor(ssum, 2);
            ssum += __shfl_xor(ssum, 4);
            ssum += __shfl_xor(ssum, 8);
            rsum[mt][r] = ssum;
        }
    if (lr == 0) {
        #pragma unroll
        for (int mt = 0; mt < 2; ++mt)
            #pragma unroll
            for (int r = 0; r < 4; ++r)
                redS[nh * 128 + mq * 32 + mt * 16 + lg * 4 + r] = rsum[mt][r];
    }
    LGKM0(); BAR();

    // ---- P write (over QK region) + VT0 write ----
    #pragma unroll
    for (int mt = 0; mt < 2; ++mt)
        #pragma unroll
        for (int r = 0; r < 4; ++r) {
            int t = mq * 32 + mt * 16 + lg * 4 + r;
            float inv = 1.0f / (redS[t] + redS[128 + t]);
            #pragma unroll
            for (int nt = 0; nt < 4; ++nt) {
                int s = nh * 64 + nt * 16 + lr;
                *(unsigned short*)(lds + LDS_QK + t * 256 + ((s * 2) ^ ((t & 7) << 4)))
                    = f2bf(sacc[mt][nt][r] * inv);
            }
        }
    {
        char* vt = lds + LDS_VT;            // slot 0
        #pragma unroll
        for (int mt = 0; mt < 2; ++mt) {
            int dl = nh * 16 + lr;
            int s0 = mq * 32 + mt * 16 + lg * 4;
            *(uint2*)(vt + dl * 256 + ((s0 * 2) ^ ((dl & 7) << 4))) = vreg[0][mt];
        }
    }
    LGKM0(); BAR();

    // ---- PV phases: O chunk -> bufX (X dead) ----
    #pragma unroll
    for (int c = 0; c < 8; ++c) {
        if (c < 7) {
            char* vt = lds + LDS_VT + ((c + 1) & 1) * 8192;
            #pragma unroll
            for (int mt = 0; mt < 2; ++mt) {
                int dl = nh * 16 + lr;
                int s0 = mq * 32 + mt * 16 + lg * 4;
                *(uint2*)(vt + dl * 256 + ((s0 * 2) ^ ((dl & 7) << 4))) = vreg[c + 1][mt];
            }
        }
        const char* vt = lds + LDS_VT + (c & 1) * 8192;
        f32x4 oacc[2];
        oacc[0] = f32x4{0.f,0.f,0.f,0.f};
        oacc[1] = f32x4{0.f,0.f,0.f,0.f};
        #pragma unroll
        for (int ks = 0; ks < 4; ++ks) {
            int sb = ks * 64 + lg * 16;
            short8 pa0 = *(const short8*)(lds + LDS_QK + am0 * 256 + (sb ^ ((am0 & 7) << 4)));
            short8 pa1 = *(const short8*)(lds + LDS_QK + am1 * 256 + (sb ^ ((am1 & 7) << 4)));
            int dl = nh * 16 + lr;
            short8 vb = *(const short8*)(vt + dl * 256 + (sb ^ ((dl & 7) << 4)));
            oacc[0] = __builtin_amdgcn_mfma_f32_16x16x32_bf16(pa0, vb, oacc[0], 0, 0, 0);
            oacc[1] = __builtin_amdgcn_mfma_f32_16x16x32_bf16(pa1, vb, oacc[1], 0, 0, 0);
        }
        #pragma unroll
        for (int mt = 0; mt < 2; ++mt)
            #pragma unroll
            for (int r = 0; r < 4; ++r) {
                int t = mq * 32 + mt * 16 + lg * 4 + r;
                int d = c * 32 + nh * 16 + lr;
                *(unsigned short*)(lds + t * 512 + ((d * 2) ^ ((t & 7) << 4))) = f2bf(oacc[mt][r]);
            }
        LGKM0(); BAR();
    }

    // ---- output projection: OUT = O * Wp^T + bp ----
    #pragma unroll
    for (int c = 0; c < 8; ++c) {
        int j = 24 + c;
        if (j + 2 < 32) issue_chunk(j + 2);
        f32x4 acc[2];
        proj_mm(0, j % 3, acc);
        int e = c * 32 + nh * 16 + lr;
        float bias = bp[e];
        #pragma unroll
        for (int mt = 0; mt < 2; ++mt)
            #pragma unroll
            for (int r = 0; r < 4; ++r) {
                int t = mq * 32 + mt * 16 + lg * 4 + r;
                out[((size_t)bid * TT + t) * DD + e] = acc[mt][r] + bias;
            }
        if (c < 6)      { LGKM0(); VMCNT2(); BAR(); }
        else if (c == 6){ LGKM0(); VMCNT0(); BAR(); }
    }
}

extern "C" void kernel_launch(void* const* d_in, const int* in_sizes, int n_in,
                              void* d_out, int out_size, void* d_ws, size_t ws_size,
                              hipStream_t stream) {
    (void)in_sizes; (void)n_in; (void)out_size; (void)ws_size; // needs ws_size >= 20054016
    const float* x  = (const float*)d_in[0];
    const float* Wq = (const float*)d_in[1];
    const float* bq = (const float*)d_in[2];
    const float* Wk = (const float*)d_in[3];
    const float* bk = (const float*)d_in[4];
    const float* Wv = (const float*)d_in[5];
    const float* bv = (const float*)d_in[6];
    const float* Wp = (const float*)d_in[7];
    const float* bp = (const float*)d_in[8];
    char* ws = (char*)d_ws;

    convert_pre<<<dim3(2048), dim3(256), 0, stream>>>(x, Wq, Wk, Wv, Wp, ws);
    hipFuncSetAttribute((const void*)mha_fused,
                        hipFuncAttributeMaxDynamicSharedMemorySize, 163840);
    mha_fused<<<dim3(2048), dim3(512), 163840, stream>>>(
        ws, bq, bk, bv, bp, (float*)d_out);
}